// Round 2
// baseline (1279.647 us; speedup 1.0000x reference)
//
#include <hip/hip_runtime.h>
#include <math.h>

#define BB 2
#define CC 192
#define DD 32
#define HH 48
#define WW 48
#define HWs (HH*WW)            // 2304
#define SS (DD*HH*WW)          // 73728
#define BS (BB*SS)             // 147456
#define NTOT (BB*CC*SS)        // 28311552
#define EPSV 1e-6f

typedef unsigned short ushort;

__device__ __forceinline__ ushort pack_bf16(float x) {
    unsigned u = __float_as_uint(x);
    u += 0x7FFFu + ((u >> 16) & 1u);
    return (ushort)(u >> 16);
}
__device__ __forceinline__ float unpack_bf16(ushort h) {
    return __uint_as_float(((unsigned)h) << 16);
}

// ---------------- K1: channel LayerNorm stats + a = silu(qk) (bf16) --------
__global__ __launch_bounds__(256) void k1_ln_a(
    const float* __restrict__ xs, const float* __restrict__ xt,
    const float* __restrict__ ln_w, const float* __restrict__ ln_b,
    const float* __restrict__ qk_sp_w, const float* __restrict__ qk_sp_b,
    const float* __restrict__ qk_tm_w, const float* __restrict__ qk_tm_b,
    ushort* __restrict__ a_out, float* __restrict__ stats)
{
    __shared__ float w_lnw[CC], w_lnb[CC], w_qsw[CC], w_qsb[CC], w_qtw[CC], w_qtb[CC];
    int tid = threadIdx.x;
    if (tid < CC) {
        w_lnw[tid] = ln_w[tid];  w_lnb[tid] = ln_b[tid];
        w_qsw[tid] = qk_sp_w[tid]; w_qsb[tid] = qk_sp_b[tid];
        w_qtw[tid] = qk_tm_w[tid]; w_qtb[tid] = qk_tm_b[tid];
    }
    __syncthreads();
    int p = blockIdx.x * 256 + tid;          // [0, BS)
    int b = p / SS, s = p % SS;
    const float* xsp = xs + (size_t)b * CC * SS + s;
    const float* xtp = xt + (size_t)b * CC * SS + s;

    float sum = 0.f, ssum = 0.f;
    #pragma unroll 8
    for (int c = 0; c < CC; ++c) {
        float v = xsp[(size_t)c * SS];
        sum += v; ssum += v * v;
    }
    float mean = sum * (1.0f / CC);
    float var  = ssum * (1.0f / CC) - mean * mean;
    float rstd = rsqrtf(var + EPSV);
    stats[p] = mean;
    stats[BS + p] = rstd;

    ushort* ap = a_out + (size_t)b * CC * SS + s;
    #pragma unroll 4
    for (int c = 0; c < CC; ++c) {
        float v = xsp[(size_t)c * SS];
        float t = xtp[(size_t)c * SS];
        float xn = (v - mean) * rstd * w_lnw[c] + w_lnb[c];
        float qk = xn * w_qsw[c] + w_qsb[c] + t * w_qtw[c] + w_qtb[c];
        float av = qk / (1.f + __expf(-qk));   // silu
        ap[(size_t)c * SS] = pack_bf16(av);
    }
}

// ---------------- K2: depthwise dilated conv + v-recompute + x + ssq --------
// Tile: d planes [d0-3, d0+10], h rows [h0-3, h0+10], w full (stored +4 offset, row 60)
#define DT 8
#define HT 8
#define TD 14
#define TH 14
#define TWD 60
#define TILE_N (TD*TH*TWD)   // 11760

__global__ __launch_bounds__(192) void k2_conv(
    const ushort* __restrict__ a_in, const float* __restrict__ xs,
    const float* __restrict__ xt, const float* __restrict__ stats,
    const float* __restrict__ attn_w, const float* __restrict__ attn_b,
    const float* __restrict__ ln_w, const float* __restrict__ ln_b,
    const float* __restrict__ v_sp_w, const float* __restrict__ v_sp_b,
    const float* __restrict__ v_tm_w, const float* __restrict__ v_tm_b,
    ushort* __restrict__ x_out, float* __restrict__ ssq)
{
    __shared__ float tile[TILE_N];
    __shared__ float wts[64];
    __shared__ float red[4];
    int tid = threadIdx.x;
    int blk = blockIdx.x;                 // bc*24 + dc*6 + hc
    int bc = blk / 24;
    int rem = blk % 24;
    int d0 = (rem / 6) * DT;
    int h0 = (rem % 6) * HT;
    int b = bc / CC, c = bc % CC;

    const ushort* abase = a_in + (size_t)bc * SS;
    for (int i = tid; i < TILE_N; i += 192) {
        int dz = i / (TH*TWD); int r = i % (TH*TWD);
        int hz = r / TWD, wz = r % TWD;
        int gd = d0 - 3 + dz, gh = h0 - 3 + hz, gw = wz - 4;
        float v = 0.f;
        if ((unsigned)gd < DD && (unsigned)gh < HH && (unsigned)gw < WW)
            v = unpack_bf16(abase[gd * HWs + gh * WW + gw]);
        tile[i] = v;
    }
    if (tid < 64) wts[tid] = attn_w[c * 64 + tid];
    float bias = attn_b[c];
    float lnw = ln_w[c], lnb = ln_b[c];
    float vsw = v_sp_w[c], vsb = v_sp_b[c];
    float vtw = v_tm_w[c], vtb = v_tm_b[c];
    __syncthreads();

    // task decomposition: exactly 192 tasks, 1 per thread.
    // thread computes outputs (od0, od0+2) x 8 w positions
    int ws = tid % 6;                 // w strip
    int oh = (tid / 6) % 8;           // local h
    int pq = tid / 48;                // 0..3
    int od0 = (pq >> 1) * 4 + (pq & 1);   // {0,1,4,5}
    int ow0 = ws * 8;

    float acc0[8], acc1[8];
    #pragma unroll
    for (int j = 0; j < 8; ++j) { acc0[j] = 0.f; acc1[j] = 0.f; }

    #pragma unroll
    for (int j = 0; j < 5; ++j) {
        int dz = od0 + 2 * j;                 // tile plane for this tap
        #pragma unroll
        for (int kh = 0; kh < 4; ++kh) {
            int hz = oh + 2 * kh;
            const float* rp = &tile[(dz * TH + hz) * TWD + ow0];
            float win[16];
            ((float4*)win)[0] = *(const float4*)(rp);
            ((float4*)win)[1] = *(const float4*)(rp + 4);
            ((float4*)win)[2] = *(const float4*)(rp + 8);
            ((float4*)win)[3] = *(const float4*)(rp + 12);
            if (j < 4) {
                float w0[4];
                *(float4*)w0 = *(const float4*)&wts[(j * 4 + kh) * 4];
                #pragma unroll
                for (int kw = 0; kw < 4; ++kw) {
                    float wk = w0[kw];
                    #pragma unroll
                    for (int jj = 0; jj < 8; ++jj)
                        acc0[jj] = fmaf(win[jj + 1 + 2 * kw], wk, acc0[jj]);
                }
            }
            if (j >= 1) {
                float w1[4];
                *(float4*)w1 = *(const float4*)&wts[((j - 1) * 4 + kh) * 4];
                #pragma unroll
                for (int kw = 0; kw < 4; ++kw) {
                    float wk = w1[kw];
                    #pragma unroll
                    for (int jj = 0; jj < 8; ++jj)
                        acc1[jj] = fmaf(win[jj + 1 + 2 * kw], wk, acc1[jj]);
                }
            }
        }
    }

    float ssql = 0.f;
    int ohg = h0 + oh;
    auto epi = [&](float (&acc)[8], int od) {
        int odg = d0 + od;
        int spat = odg * HWs + ohg * WW + ow0;
        size_t g = (size_t)bc * SS + spat;
        int sp = b * SS + spat;
        float xsv[8], xtv[8], mnv[8], rsv[8];
        ((float4*)xsv)[0] = *(const float4*)&xs[g];
        ((float4*)xsv)[1] = *(const float4*)&xs[g + 4];
        ((float4*)xtv)[0] = *(const float4*)&xt[g];
        ((float4*)xtv)[1] = *(const float4*)&xt[g + 4];
        ((float4*)mnv)[0] = *(const float4*)&stats[sp];
        ((float4*)mnv)[1] = *(const float4*)&stats[sp + 4];
        ((float4*)rsv)[0] = *(const float4*)&stats[BS + sp];
        ((float4*)rsv)[1] = *(const float4*)&stats[BS + sp + 4];
        ushort pk[8];
        #pragma unroll
        for (int jj = 0; jj < 8; ++jj) {
            float xn = (xsv[jj] - mnv[jj]) * rsv[jj] * lnw + lnb;
            float vv = xn * vsw + vsb + xtv[jj] * vtw + vtb;
            float xo = (acc[jj] + bias) * vv;
            ssql += xo * xo;
            pk[jj] = pack_bf16(xo);
        }
        *(uint4*)&x_out[g] = *(uint4*)pk;
    };
    epi(acc0, od0);
    epi(acc1, od0 + 2);

    // block reduce ssql (192 threads = 3 waves)
    int lane = tid & 63, wid = tid >> 6;
    #pragma unroll
    for (int off = 32; off > 0; off >>= 1)
        ssql += __shfl_down(ssql, off);
    if (lane == 0) red[wid] = ssql;
    __syncthreads();
    if (tid == 0) atomicAdd(&ssq[bc], red[0] + red[1] + red[2]);
}

// ---------------- K3: GRN scalars -> per-(b,c) A, B2 ----------------------
__global__ __launch_bounds__(384) void k3_scale(
    const float* __restrict__ ssq,
    const float* __restrict__ grn_gamma, const float* __restrict__ grn_beta,
    const float* __restrict__ proj_w, const float* __restrict__ proj_b,
    float* __restrict__ AB)
{
    __shared__ float gxs[BB*CC];
    __shared__ float msum[BB];
    int tid = threadIdx.x;     // 384
    float gx = sqrtf(ssq[tid]);
    gxs[tid] = gx;
    __syncthreads();
    if (tid < BB) {
        float s = 0.f;
        for (int c2 = 0; c2 < CC; ++c2) s += gxs[tid * CC + c2];
        msum[tid] = s * (1.0f / CC);
    }
    __syncthreads();
    int b = tid / CC, c2 = tid % CC;
    float nx = gx / (msum[b] + EPSV);
    float A  = proj_w[c2] * (1.f + grn_gamma[c2] * nx);
    float B2 = proj_w[c2] * grn_beta[c2] + proj_b[c2];
    AB[tid] = A;
    AB[BB*CC + tid] = B2;
}

// ---------------- K4: out = xs + A*x + B2 ---------------------------------
__global__ __launch_bounds__(256) void k4_final(
    const float* __restrict__ xs, const ushort* __restrict__ xv,
    const float* __restrict__ AB, float* __restrict__ out)
{
    int i = blockIdx.x * 256 + threadIdx.x;    // 8-elem index
    size_t g = (size_t)i * 8;
    int bc = (int)(g / SS);
    float A  = AB[bc];
    float B2 = AB[BB*CC + bc];
    uint4 xr = *(const uint4*)&xv[g];
    ushort hx[8];
    *(uint4*)hx = xr;
    float4 s0 = *(const float4*)&xs[g];
    float4 s1 = *(const float4*)&xs[g + 4];
    float o[8];
    float sv[8] = {s0.x, s0.y, s0.z, s0.w, s1.x, s1.y, s1.z, s1.w};
    #pragma unroll
    for (int jj = 0; jj < 8; ++jj)
        o[jj] = fmaf(A, unpack_bf16(hx[jj]), sv[jj]) + B2;
    *(float4*)&out[g]     = ((float4*)o)[0];
    *(float4*)&out[g + 4] = ((float4*)o)[1];
}

extern "C" void kernel_launch(void* const* d_in, const int* in_sizes, int n_in,
                              void* d_out, int out_size, void* d_ws, size_t ws_size,
                              hipStream_t stream) {
    const float* xs      = (const float*)d_in[0];
    const float* xt      = (const float*)d_in[1];
    const float* ln_w    = (const float*)d_in[2];
    const float* ln_b    = (const float*)d_in[3];
    const float* qk_sp_w = (const float*)d_in[4];
    const float* qk_sp_b = (const float*)d_in[5];
    const float* v_sp_w  = (const float*)d_in[6];
    const float* v_sp_b  = (const float*)d_in[7];
    const float* qk_tm_w = (const float*)d_in[8];
    const float* qk_tm_b = (const float*)d_in[9];
    const float* v_tm_w  = (const float*)d_in[10];
    const float* v_tm_b  = (const float*)d_in[11];
    const float* attn_w  = (const float*)d_in[12];
    const float* attn_b  = (const float*)d_in[13];
    const float* grn_g   = (const float*)d_in[14];
    const float* grn_b   = (const float*)d_in[15];
    const float* proj_w  = (const float*)d_in[16];
    const float* proj_b  = (const float*)d_in[17];
    float* out = (float*)d_out;

    ushort* a_buf = (ushort*)d_ws;                    // NTOT bf16
    ushort* x_buf = a_buf + (size_t)NTOT;             // NTOT bf16
    float* stats  = (float*)(x_buf + (size_t)NTOT);   // 2*BS f32
    float* ssq    = stats + (size_t)2*BS;             // BB*CC
    float* AB     = ssq + BB*CC;                      // 2*BB*CC

    hipMemsetAsync(ssq, 0, BB*CC*sizeof(float), stream);

    k1_ln_a<<<BS/256, 256, 0, stream>>>(xs, xt, ln_w, ln_b,
        qk_sp_w, qk_sp_b, qk_tm_w, qk_tm_b, a_buf, stats);

    k2_conv<<<BB*CC*24, 192, 0, stream>>>(a_buf, xs, xt, stats,
        attn_w, attn_b, ln_w, ln_b, v_sp_w, v_sp_b, v_tm_w, v_tm_b,
        x_buf, ssq);

    k3_scale<<<1, 384, 0, stream>>>(ssq, grn_g, grn_b, proj_w, proj_b, AB);

    k4_final<<<NTOT/8/256, 256, 0, stream>>>(xs, x_buf, AB, out);
}

// Round 5
// 885.615 us; speedup vs baseline: 1.4449x; 1.4449x over previous
//
#include <hip/hip_runtime.h>
#include <math.h>

#define BB 2
#define CC 192
#define DD 32
#define HH 48
#define WW 48
#define HWs (HH*WW)            // 2304
#define SS (DD*HH*WW)          // 73728
#define BS (BB*SS)             // 147456
#define NTOT (BB*CC*SS)        // 28311552
#define EPSV 1e-6f

typedef unsigned short ushort;

__device__ __forceinline__ ushort pack_bf16(float x) {
    unsigned u = __float_as_uint(x);
    u += 0x7FFFu + ((u >> 16) & 1u);
    return (ushort)(u >> 16);
}
__device__ __forceinline__ float bf16_lo(unsigned u) { return __uint_as_float(u << 16); }
__device__ __forceinline__ float bf16_hi(unsigned u) { return __uint_as_float(u & 0xFFFF0000u); }

// ---------------- K1: LayerNorm + a = silu(qk), v (both bf16) --------------
__global__ __launch_bounds__(256) void k1_ln_av(
    const float* __restrict__ xs, const float* __restrict__ xt,
    const float* __restrict__ ln_w, const float* __restrict__ ln_b,
    const float* __restrict__ qk_sp_w, const float* __restrict__ qk_sp_b,
    const float* __restrict__ v_sp_w, const float* __restrict__ v_sp_b,
    const float* __restrict__ qk_tm_w, const float* __restrict__ qk_tm_b,
    const float* __restrict__ v_tm_w, const float* __restrict__ v_tm_b,
    ushort* __restrict__ a_out, ushort* __restrict__ v_out)
{
    __shared__ float w_lnw[CC], w_lnb[CC], w_qsw[CC], w_qsb[CC], w_qtw[CC], w_qtb[CC];
    __shared__ float w_vsw[CC], w_vsb[CC], w_vtw[CC], w_vtb[CC];
    int tid = threadIdx.x;
    if (tid < CC) {
        w_lnw[tid] = ln_w[tid];  w_lnb[tid] = ln_b[tid];
        w_qsw[tid] = qk_sp_w[tid]; w_qsb[tid] = qk_sp_b[tid];
        w_qtw[tid] = qk_tm_w[tid]; w_qtb[tid] = qk_tm_b[tid];
        w_vsw[tid] = v_sp_w[tid]; w_vsb[tid] = v_sp_b[tid];
        w_vtw[tid] = v_tm_w[tid]; w_vtb[tid] = v_tm_b[tid];
    }
    __syncthreads();
    int p = blockIdx.x * 256 + tid;          // [0, BS)
    int b = p / SS, s = p % SS;
    const float* xsp = xs + (size_t)b * CC * SS + s;
    const float* xtp = xt + (size_t)b * CC * SS + s;

    float sum = 0.f, ssum = 0.f;
    #pragma unroll 8
    for (int c = 0; c < CC; ++c) {
        float v = xsp[(size_t)c * SS];
        sum += v; ssum += v * v;
    }
    float mean = sum * (1.0f / CC);
    float var  = ssum * (1.0f / CC) - mean * mean;
    float rstd = rsqrtf(var + EPSV);

    ushort* ap = a_out + (size_t)b * CC * SS + s;
    ushort* vp = v_out + (size_t)b * CC * SS + s;
    #pragma unroll 4
    for (int c = 0; c < CC; ++c) {
        float xv = xsp[(size_t)c * SS];
        float tv = xtp[(size_t)c * SS];
        float xn = (xv - mean) * rstd * w_lnw[c] + w_lnb[c];
        float qk = xn * w_qsw[c] + w_qsb[c] + tv * w_qtw[c] + w_qtb[c];
        float vv = xn * w_vsw[c] + w_vsb[c] + tv * w_vtw[c] + w_vtb[c];
        float av = qk / (1.f + __expf(-qk));   // silu
        ap[(size_t)c * SS] = pack_bf16(av);
        vp[(size_t)c * SS] = pack_bf16(vv);
    }
}

// ---------------- K2: depthwise dilated conv + gate + ssq ------------------
// Block: (bc, 4 od planes, 24 oh rows). 192 threads; thread owns 24-w strip.
// LDS tile: 10 planes x 30 rows x 56 ushorts (row = 4 zero | 48 data | 4 zero)
#define ODT 4
#define OHT 24
#define NP 10
#define NR 30
#define RSD 28        // row stride in dwords
#define PSD (NR*RSD)  // 840 plane stride in dwords
#define TILE_DW (NP*PSD)  // 8400 dwords = 33.6 KB

__global__ __launch_bounds__(192) void k2_conv(
    const ushort* __restrict__ a_in, const ushort* __restrict__ v_in,
    const float* __restrict__ attn_w, const float* __restrict__ attn_b,
    ushort* __restrict__ x_out, float* __restrict__ ssq)
{
    __shared__ unsigned tile[TILE_DW];
    __shared__ float wts[64];
    __shared__ float red[3];
    int tid = threadIdx.x;
    int blk = blockIdx.x;                 // bc*16 + odt*2 + oht
    int bc = blk >> 4;
    int rem = blk & 15;
    int d0 = (rem >> 1) * ODT;
    int h0 = (rem & 1) * OHT;
    int c = bc % CC;

    // ---- stage tile (u32 = bf16 pair), zero halo ----
    const ushort* abase = a_in + (size_t)bc * SS;
    for (int i = tid; i < TILE_DW; i += 192) {
        int p = i / PSD;
        int r2 = i - p * PSD;
        int r = r2 / RSD;
        int q2 = r2 - r * RSD;
        int id = d0 - 3 + p;
        int ih = h0 - 3 + r;
        int iw = q2 * 2 - 4;
        unsigned val = 0;
        if ((unsigned)id < (unsigned)DD && (unsigned)ih < (unsigned)HH &&
            (unsigned)iw < 47u)
            val = *(const unsigned*)(abase + (size_t)id * HWs + ih * WW + iw);
        tile[i] = val;
    }
    if (tid < 64) wts[tid] = attn_w[c * 64 + tid];
    __syncthreads();
    float bias = attn_b[c];

    int half = tid & 1;
    int ohl = (tid >> 1) % 24;
    int odl = tid / 48;
    int ow0 = half * 24;

    float acc[24];
    #pragma unroll
    for (int j = 0; j < 24; ++j) acc[j] = 0.f;

    #pragma unroll
    for (int kd = 0; kd < 4; ++kd) {
        int p = odl + 2 * kd;
        #pragma unroll
        for (int kh = 0; kh < 4; ++kh) {
            int r = ohl + 2 * kh;
            int bd = p * PSD + r * RSD + half * 12;
            unsigned u[16];
            *(uint4*)&u[0]  = *(const uint4*)&tile[bd];
            *(uint4*)&u[4]  = *(const uint4*)&tile[bd + 4];
            *(uint4*)&u[8]  = *(const uint4*)&tile[bd + 8];
            *(uint4*)&u[12] = *(const uint4*)&tile[bd + 12];
            float wf[32];
            #pragma unroll
            for (int m = 0; m < 16; ++m) {
                wf[2*m]   = bf16_lo(u[m]);
                wf[2*m+1] = bf16_hi(u[m]);
            }
            float4 wv = *(const float4*)&wts[(kd * 4 + kh) * 4];
            #pragma unroll
            for (int j = 0; j < 24; ++j) {
                float a0 = fmaf(wf[j + 1], wv.x, acc[j]);
                float a1 = fmaf(wf[j + 3], wv.y, a0);
                float a2 = fmaf(wf[j + 5], wv.z, a1);
                acc[j]   = fmaf(wf[j + 7], wv.w, a2);
            }
        }
    }

    // ---- epilogue: x = (conv+bias)*v, ssq ----
    int od = d0 + odl, oh = h0 + ohl;
    size_t g = (size_t)bc * SS + (size_t)od * HWs + oh * WW + ow0;
    unsigned uv[12];
    *(uint4*)&uv[0] = *(const uint4*)(v_in + g);
    *(uint4*)&uv[4] = *(const uint4*)(v_in + g + 8);
    *(uint4*)&uv[8] = *(const uint4*)(v_in + g + 16);
    float ssql = 0.f;
    ushort pk[24];
    #pragma unroll
    for (int m = 0; m < 12; ++m) {
        float v0 = bf16_lo(uv[m]);
        float v1 = bf16_hi(uv[m]);
        float x0 = (acc[2*m]     + bias) * v0;
        float x1 = (acc[2*m + 1] + bias) * v1;
        ssql += x0 * x0 + x1 * x1;
        pk[2*m]     = pack_bf16(x0);
        pk[2*m + 1] = pack_bf16(x1);
    }
    *(uint4*)&x_out[g]      = *(uint4*)&pk[0];
    *(uint4*)&x_out[g + 8]  = *(uint4*)&pk[8];
    *(uint4*)&x_out[g + 16] = *(uint4*)&pk[16];

    // ---- block reduce ssql (3 waves) ----
    #pragma unroll
    for (int off = 32; off > 0; off >>= 1)
        ssql += __shfl_down(ssql, off);
    int lane = tid & 63, wid = tid >> 6;
    if (lane == 0) red[wid] = ssql;
    __syncthreads();
    if (tid == 0) atomicAdd(&ssq[bc], red[0] + red[1] + red[2]);
}

// ---------------- K3: GRN scalars -> per-(b,c) A, B2 ----------------------
__global__ __launch_bounds__(384) void k3_scale(
    const float* __restrict__ ssq,
    const float* __restrict__ grn_gamma, const float* __restrict__ grn_beta,
    const float* __restrict__ proj_w, const float* __restrict__ proj_b,
    float* __restrict__ AB)
{
    __shared__ float gxs[BB*CC];
    __shared__ float msum[BB];
    int tid = threadIdx.x;     // 384
    float gx = sqrtf(ssq[tid]);
    gxs[tid] = gx;
    __syncthreads();
    if (tid < BB) {
        float s = 0.f;
        for (int c2 = 0; c2 < CC; ++c2) s += gxs[tid * CC + c2];
        msum[tid] = s * (1.0f / CC);
    }
    __syncthreads();
    int b = tid / CC, c2 = tid % CC;
    float nx = gx / (msum[b] + EPSV);
    float A  = proj_w[c2] * (1.f + grn_gamma[c2] * nx);
    float B2 = proj_w[c2] * grn_beta[c2] + proj_b[c2];
    AB[tid] = A;
    AB[BB*CC + tid] = B2;
}

// ---------------- K4: out = xs + A*x + B2 ---------------------------------
__global__ __launch_bounds__(256) void k4_final(
    const float* __restrict__ xs, const ushort* __restrict__ xv,
    const float* __restrict__ AB, float* __restrict__ out)
{
    int i = blockIdx.x * 256 + threadIdx.x;    // 8-elem index
    size_t g = (size_t)i * 8;
    int bc = (int)(g / SS);
    float A  = AB[bc];
    float B2 = AB[BB*CC + bc];
    uint4 xr = *(const uint4*)&xv[g];
    unsigned hx[4];
    *(uint4*)hx = xr;
    float4 s0 = *(const float4*)&xs[g];
    float4 s1 = *(const float4*)&xs[g + 4];
    float o[8];
    float sv[8] = {s0.x, s0.y, s0.z, s0.w, s1.x, s1.y, s1.z, s1.w};
    #pragma unroll
    for (int m = 0; m < 4; ++m) {
        o[2*m]   = fmaf(A, bf16_lo(hx[m]), sv[2*m])   + B2;
        o[2*m+1] = fmaf(A, bf16_hi(hx[m]), sv[2*m+1]) + B2;
    }
    *(float4*)&out[g]     = ((float4*)o)[0];
    *(float4*)&out[g + 4] = ((float4*)o)[1];
}

extern "C" void kernel_launch(void* const* d_in, const int* in_sizes, int n_in,
                              void* d_out, int out_size, void* d_ws, size_t ws_size,
                              hipStream_t stream) {
    const float* xs      = (const float*)d_in[0];
    const float* xt      = (const float*)d_in[1];
    const float* ln_w    = (const float*)d_in[2];
    const float* ln_b    = (const float*)d_in[3];
    const float* qk_sp_w = (const float*)d_in[4];
    const float* qk_sp_b = (const float*)d_in[5];
    const float* v_sp_w  = (const float*)d_in[6];
    const float* v_sp_b  = (const float*)d_in[7];
    const float* qk_tm_w = (const float*)d_in[8];
    const float* qk_tm_b = (const float*)d_in[9];
    const float* v_tm_w  = (const float*)d_in[10];
    const float* v_tm_b  = (const float*)d_in[11];
    const float* attn_w  = (const float*)d_in[12];
    const float* attn_b  = (const float*)d_in[13];
    const float* grn_g   = (const float*)d_in[14];
    const float* grn_b   = (const float*)d_in[15];
    const float* proj_w  = (const float*)d_in[16];
    const float* proj_b  = (const float*)d_in[17];
    float* out = (float*)d_out;

    ushort* a_buf = (ushort*)d_ws;                    // NTOT bf16
    ushort* v_buf = a_buf + (size_t)NTOT;             // NTOT bf16
    ushort* x_buf = v_buf + (size_t)NTOT;             // NTOT bf16
    float* ssq    = (float*)(x_buf + (size_t)NTOT);   // BB*CC
    float* AB     = ssq + BB*CC;                      // 2*BB*CC

    hipMemsetAsync(ssq, 0, BB*CC*sizeof(float), stream);

    k1_ln_av<<<BS/256, 256, 0, stream>>>(xs, xt, ln_w, ln_b,
        qk_sp_w, qk_sp_b, v_sp_w, v_sp_b,
        qk_tm_w, qk_tm_b, v_tm_w, v_tm_b, a_buf, v_buf);

    k2_conv<<<BB*CC*16, 192, 0, stream>>>(a_buf, v_buf,
        attn_w, attn_b, x_buf, ssq);

    k3_scale<<<1, 384, 0, stream>>>(ssq, grn_g, grn_b, proj_w, proj_b, AB);

    k4_final<<<NTOT/8/256, 256, 0, stream>>>(xs, x_buf, AB, out);
}

// Round 6
// 812.427 us; speedup vs baseline: 1.5751x; 1.0901x over previous
//
#include <hip/hip_runtime.h>
#include <math.h>

#define BB 2
#define CC 192
#define DD 32
#define HH 48
#define WW 48
#define HWs (HH*WW)            // 2304
#define SS (DD*HH*WW)          // 73728
#define BS (BB*SS)             // 147456
#define NTOT (BB*CC*SS)        // 28311552
#define EPSV 1e-6f

typedef unsigned short ushort;

__device__ __forceinline__ ushort pack_bf16(float x) {
    unsigned u = __float_as_uint(x);
    u += 0x7FFFu + ((u >> 16) & 1u);
    return (ushort)(u >> 16);
}
__device__ __forceinline__ float bf16_lo(unsigned u) { return __uint_as_float(u << 16); }
__device__ __forceinline__ float bf16_hi(unsigned u) { return __uint_as_float(u & 0xFFFF0000u); }

// ---------------- K1: LayerNorm + a = silu(qk), v (both bf16) --------------
// Block: 256 thr = 4 waves; 64 spatial positions; each wave owns 48 channels.
// xs kept in registers between the stat pass and the output pass.
#define CG 48
__global__ __launch_bounds__(256) void k1_ln_av(
    const float* __restrict__ xs, const float* __restrict__ xt,
    const float* __restrict__ ln_w, const float* __restrict__ ln_b,
    const float* __restrict__ qk_sp_w, const float* __restrict__ qk_sp_b,
    const float* __restrict__ v_sp_w, const float* __restrict__ v_sp_b,
    const float* __restrict__ qk_tm_w, const float* __restrict__ qk_tm_b,
    const float* __restrict__ v_tm_w, const float* __restrict__ v_tm_b,
    ushort* __restrict__ a_out, ushort* __restrict__ v_out)
{
    __shared__ float w_all[10][CC];
    __shared__ float sred[2][4][64];
    int tid = threadIdx.x;
    if (tid < CC) {
        w_all[0][tid] = ln_w[tid];   w_all[1][tid] = ln_b[tid];
        w_all[2][tid] = qk_sp_w[tid]; w_all[3][tid] = qk_sp_b[tid];
        w_all[4][tid] = qk_tm_w[tid]; w_all[5][tid] = qk_tm_b[tid];
        w_all[6][tid] = v_sp_w[tid];  w_all[7][tid] = v_sp_b[tid];
        w_all[8][tid] = v_tm_w[tid];  w_all[9][tid] = v_tm_b[tid];
    }
    __syncthreads();

    int tx = tid & 63, wy = tid >> 6;
    int p0 = blockIdx.x * 64;               // SS % 64 == 0, so one b per block
    int b = p0 / SS;
    int s = (p0 % SS) + tx;

    const float* xsp = xs + ((size_t)(b * CC + wy * CG)) * SS + s;
    float xv[CG];
    float sum = 0.f, ssum = 0.f;
    #pragma unroll
    for (int i = 0; i < CG; ++i) {
        float v = xsp[(size_t)i * SS];
        xv[i] = v; sum += v; ssum += v * v;
    }
    sred[0][wy][tx] = sum;
    sred[1][wy][tx] = ssum;
    __syncthreads();
    sum  = sred[0][0][tx] + sred[0][1][tx] + sred[0][2][tx] + sred[0][3][tx];
    ssum = sred[1][0][tx] + sred[1][1][tx] + sred[1][2][tx] + sred[1][3][tx];
    float mean = sum * (1.0f / CC);
    float var  = ssum * (1.0f / CC) - mean * mean;
    float rstd = rsqrtf(var + EPSV);

    const float* xtp = xt + ((size_t)(b * CC + wy * CG)) * SS + s;
    ushort* ap = a_out + ((size_t)(b * CC + wy * CG)) * SS + s;
    ushort* vp = v_out + ((size_t)(b * CC + wy * CG)) * SS + s;
    #pragma unroll
    for (int i = 0; i < CG; ++i) {
        int c = wy * CG + i;
        float t  = xtp[(size_t)i * SS];
        float xn = (xv[i] - mean) * rstd * w_all[0][c] + w_all[1][c];
        float qk = xn * w_all[2][c] + w_all[3][c] + t * w_all[4][c] + w_all[5][c];
        float vv = xn * w_all[6][c] + w_all[7][c] + t * w_all[8][c] + w_all[9][c];
        float av = qk / (1.f + __expf(-qk));   // silu
        ap[(size_t)i * SS] = pack_bf16(av);
        vp[(size_t)i * SS] = pack_bf16(vv);
    }
}

// ---------------- K2: depthwise dilated conv + gate + ssq ------------------
// Block: (bc, 4 od planes, 24 oh rows), 576 threads; thread owns 8-w strip.
// LDS tile: 10 planes x 30 rows x 56 ushorts (row = 4 zero | 48 data | 4 zero)
#define ODT 4
#define OHT 24
#define NP 10
#define NR 30
#define RSD 28        // row stride in dwords
#define PSD (NR*RSD)  // 840 plane stride in dwords
#define TILE_DW (NP*PSD)  // 8400 dwords = 33.6 KB

__global__ __launch_bounds__(576, 5) void k2_conv(
    const ushort* __restrict__ a_in, const ushort* __restrict__ v_in,
    const float* __restrict__ attn_w, const float* __restrict__ attn_b,
    ushort* __restrict__ x_out, float* __restrict__ ssq)
{
    __shared__ unsigned tile[TILE_DW];
    __shared__ float wts[64];
    int tid = threadIdx.x;
    int blk = blockIdx.x;                 // bc*16 + odc*2 + ohc
    int bc = blk >> 4;
    int rem = blk & 15;
    int d0 = (rem >> 1) * ODT;
    int h0 = (rem & 1) * OHT;
    int c = bc % CC;

    // ---- stage tile (u32 = bf16 pair), zero halo ----
    const ushort* abase = a_in + (size_t)bc * SS;
    for (int i = tid; i < TILE_DW; i += 576) {
        int p = i / PSD;
        int r2 = i - p * PSD;
        int r = r2 / RSD;
        int q2 = r2 - r * RSD;
        int id = d0 - 3 + p;
        int ih = h0 - 3 + r;
        int iw = q2 * 2 - 4;
        unsigned val = 0;
        if ((unsigned)id < (unsigned)DD && (unsigned)ih < (unsigned)HH &&
            (unsigned)iw < 47u)
            val = *(const unsigned*)(abase + (size_t)id * HWs + ih * WW + iw);
        tile[i] = val;
    }
    if (tid < 64) wts[tid] = attn_w[c * 64 + tid];
    __syncthreads();
    float bias = attn_b[c];

    // thread -> (strip, oh, od):  576 = 6 strips * 24 rows * 4 planes
    int strip = tid % 6;
    int ohl = (tid / 6) % 24;
    int odl = tid / 144;
    int ow0 = strip * 8;

    float acc[8];
    #pragma unroll
    for (int j = 0; j < 8; ++j) acc[j] = 0.f;

    #pragma unroll
    for (int kd = 0; kd < 4; ++kd) {
        int p = odl + 2 * kd;
        #pragma unroll
        for (int kh = 0; kh < 4; ++kh) {
            int r = ohl + 2 * kh;
            int bd = p * PSD + r * RSD + strip * 4;
            unsigned u[8];
            *(uint4*)&u[0] = *(const uint4*)&tile[bd];
            *(uint4*)&u[4] = *(const uint4*)&tile[bd + 4];
            float wf[16];
            #pragma unroll
            for (int m = 0; m < 8; ++m) {
                wf[2*m]   = bf16_lo(u[m]);
                wf[2*m+1] = bf16_hi(u[m]);
            }
            float4 wv = *(const float4*)&wts[(kd * 4 + kh) * 4];
            #pragma unroll
            for (int j = 0; j < 8; ++j) {
                float a0 = fmaf(wf[j + 1], wv.x, acc[j]);
                float a1 = fmaf(wf[j + 3], wv.y, a0);
                float a2 = fmaf(wf[j + 5], wv.z, a1);
                acc[j]   = fmaf(wf[j + 7], wv.w, a2);
            }
        }
    }

    // ---- epilogue: x = (conv+bias)*v, ssq ----
    int od = d0 + odl, oh = h0 + ohl;
    size_t g = (size_t)bc * SS + (size_t)od * HWs + oh * WW + ow0;
    unsigned uv[4];
    *(uint4*)&uv[0] = *(const uint4*)(v_in + g);
    float ssql = 0.f;
    ushort pk[8];
    #pragma unroll
    for (int m = 0; m < 4; ++m) {
        float v0 = bf16_lo(uv[m]);
        float v1 = bf16_hi(uv[m]);
        float x0 = (acc[2*m]     + bias) * v0;
        float x1 = (acc[2*m + 1] + bias) * v1;
        ssql += x0 * x0 + x1 * x1;
        pk[2*m]     = pack_bf16(x0);
        pk[2*m + 1] = pack_bf16(x1);
    }
    *(uint4*)&x_out[g] = *(uint4*)&pk[0];

    // ---- per-wave reduce, one atomic per wave ----
    #pragma unroll
    for (int off = 32; off > 0; off >>= 1)
        ssql += __shfl_down(ssql, off);
    if ((tid & 63) == 0) atomicAdd(&ssq[bc], ssql);
}

// ---------------- K3: GRN scalars -> per-(b,c) A, B2 ----------------------
__global__ __launch_bounds__(384) void k3_scale(
    const float* __restrict__ ssq,
    const float* __restrict__ grn_gamma, const float* __restrict__ grn_beta,
    const float* __restrict__ proj_w, const float* __restrict__ proj_b,
    float* __restrict__ AB)
{
    __shared__ float gxs[BB*CC];
    __shared__ float msum[BB];
    int tid = threadIdx.x;     // 384
    float gx = sqrtf(ssq[tid]);
    gxs[tid] = gx;
    __syncthreads();
    if (tid < BB) {
        float s = 0.f;
        for (int c2 = 0; c2 < CC; ++c2) s += gxs[tid * CC + c2];
        msum[tid] = s * (1.0f / CC);
    }
    __syncthreads();
    int b = tid / CC, c2 = tid % CC;
    float nx = gx / (msum[b] + EPSV);
    float A  = proj_w[c2] * (1.f + grn_gamma[c2] * nx);
    float B2 = proj_w[c2] * grn_beta[c2] + proj_b[c2];
    AB[tid] = A;
    AB[BB*CC + tid] = B2;
}

// ---------------- K4: out = xs + A*x + B2 ---------------------------------
__global__ __launch_bounds__(256) void k4_final(
    const float* __restrict__ xs, const ushort* __restrict__ xv,
    const float* __restrict__ AB, float* __restrict__ out)
{
    int i = blockIdx.x * 256 + threadIdx.x;    // 8-elem index
    size_t g = (size_t)i * 8;
    int bc = (int)(g / SS);
    float A  = AB[bc];
    float B2 = AB[BB*CC + bc];
    uint4 xr = *(const uint4*)&xv[g];
    unsigned hx[4];
    *(uint4*)hx = xr;
    float4 s0 = *(const float4*)&xs[g];
    float4 s1 = *(const float4*)&xs[g + 4];
    float o[8];
    float sv[8] = {s0.x, s0.y, s0.z, s0.w, s1.x, s1.y, s1.z, s1.w};
    #pragma unroll
    for (int m = 0; m < 4; ++m) {
        o[2*m]   = fmaf(A, bf16_lo(hx[m]), sv[2*m])   + B2;
        o[2*m+1] = fmaf(A, bf16_hi(hx[m]), sv[2*m+1]) + B2;
    }
    *(float4*)&out[g]     = ((float4*)o)[0];
    *(float4*)&out[g + 4] = ((float4*)o)[1];
}

extern "C" void kernel_launch(void* const* d_in, const int* in_sizes, int n_in,
                              void* d_out, int out_size, void* d_ws, size_t ws_size,
                              hipStream_t stream) {
    const float* xs      = (const float*)d_in[0];
    const float* xt      = (const float*)d_in[1];
    const float* ln_w    = (const float*)d_in[2];
    const float* ln_b    = (const float*)d_in[3];
    const float* qk_sp_w = (const float*)d_in[4];
    const float* qk_sp_b = (const float*)d_in[5];
    const float* v_sp_w  = (const float*)d_in[6];
    const float* v_sp_b  = (const float*)d_in[7];
    const float* qk_tm_w = (const float*)d_in[8];
    const float* qk_tm_b = (const float*)d_in[9];
    const float* v_tm_w  = (const float*)d_in[10];
    const float* v_tm_b  = (const float*)d_in[11];
    const float* attn_w  = (const float*)d_in[12];
    const float* attn_b  = (const float*)d_in[13];
    const float* grn_g   = (const float*)d_in[14];
    const float* grn_b   = (const float*)d_in[15];
    const float* proj_w  = (const float*)d_in[16];
    const float* proj_b  = (const float*)d_in[17];
    float* out = (float*)d_out;

    ushort* a_buf = (ushort*)d_ws;                    // NTOT bf16
    ushort* v_buf = a_buf + (size_t)NTOT;             // NTOT bf16
    ushort* x_buf = v_buf + (size_t)NTOT;             // NTOT bf16
    float* ssq    = (float*)(x_buf + (size_t)NTOT);   // BB*CC
    float* AB     = ssq + BB*CC;                      // 2*BB*CC

    hipMemsetAsync(ssq, 0, BB*CC*sizeof(float), stream);

    k1_ln_av<<<BS/64, 256, 0, stream>>>(xs, xt, ln_w, ln_b,
        qk_sp_w, qk_sp_b, v_sp_w, v_sp_b,
        qk_tm_w, qk_tm_b, v_tm_w, v_tm_b, a_buf, v_buf);

    k2_conv<<<BB*CC*16, 576, 0, stream>>>(a_buf, v_buf,
        attn_w, attn_b, x_buf, ssq);

    k3_scale<<<1, 384, 0, stream>>>(ssq, grn_g, grn_b, proj_w, proj_b, AB);

    k4_final<<<NTOT/8/256, 256, 0, stream>>>(xs, x_buf, AB, out);
}

// Round 10
// 708.784 us; speedup vs baseline: 1.8054x; 1.1462x over previous
//
#include <hip/hip_runtime.h>
#include <math.h>

#define BB 2
#define CC 192
#define DD 32
#define HH 48
#define WW 48
#define HWs (HH*WW)            // 2304
#define SS (DD*HH*WW)          // 73728
#define BS (BB*SS)             // 147456
#define NTOT (BB*CC*SS)        // 28311552
#define EPSV 1e-6f

typedef unsigned short ushort;

__device__ __forceinline__ ushort pack_bf16(float x) {
    unsigned u = __float_as_uint(x);
    u += 0x7FFFu + ((u >> 16) & 1u);
    return (ushort)(u >> 16);
}
__device__ __forceinline__ unsigned pack_bf16x2(float lo, float hi) {
    return (unsigned)pack_bf16(lo) | ((unsigned)pack_bf16(hi) << 16);
}
__device__ __forceinline__ float bf16_lo(unsigned u) { return __uint_as_float(u << 16); }
__device__ __forceinline__ float bf16_hi(unsigned u) { return __uint_as_float(u & 0xFFFF0000u); }

// ---------------- K1: LayerNorm + a = silu(qk), v (both bf16) --------------
// 2-pass, float2-vectorized. Thread owns 2 consecutive positions; c-loop is
// fully coalesced (64 lanes x 8 B = 512 B/instr). Stats live in registers;
// pass-2 xs re-read rides L3 (113 MB < 256 MB).
__global__ __launch_bounds__(256) void k1_ln_av(
    const float* __restrict__ xs, const float* __restrict__ xt,
    const float* __restrict__ ln_w, const float* __restrict__ ln_b,
    const float* __restrict__ qk_sp_w, const float* __restrict__ qk_sp_b,
    const float* __restrict__ v_sp_w, const float* __restrict__ v_sp_b,
    const float* __restrict__ qk_tm_w, const float* __restrict__ qk_tm_b,
    const float* __restrict__ v_tm_w, const float* __restrict__ v_tm_b,
    ushort* __restrict__ a_out, ushort* __restrict__ v_out)
{
    __shared__ float w_all[10][CC];
    int tid = threadIdx.x;
    if (tid < CC) {
        w_all[0][tid] = ln_w[tid];    w_all[1][tid] = ln_b[tid];
        w_all[2][tid] = qk_sp_w[tid]; w_all[3][tid] = qk_sp_b[tid];
        w_all[4][tid] = qk_tm_w[tid]; w_all[5][tid] = qk_tm_b[tid];
        w_all[6][tid] = v_sp_w[tid];  w_all[7][tid] = v_sp_b[tid];
        w_all[8][tid] = v_tm_w[tid];  w_all[9][tid] = v_tm_b[tid];
    }
    __syncthreads();

    int p0 = blockIdx.x * 512;             // SS % 512 == 0 -> one b per block
    int b = p0 / SS;
    int s = (p0 % SS) + tid * 2;

    const float* xsp = xs + (size_t)b * CC * SS + s;
    const float* xtp = xt + (size_t)b * CC * SS + s;

    float sum0 = 0.f, sum1 = 0.f, ssum0 = 0.f, ssum1 = 0.f;
    #pragma unroll 4
    for (int c = 0; c < CC; ++c) {
        float2 v = *(const float2*)(xsp + (size_t)c * SS);
        sum0 += v.x; ssum0 += v.x * v.x;
        sum1 += v.y; ssum1 += v.y * v.y;
    }
    float mean0 = sum0 * (1.0f / CC), mean1 = sum1 * (1.0f / CC);
    float rstd0 = rsqrtf(ssum0 * (1.0f / CC) - mean0 * mean0 + EPSV);
    float rstd1 = rsqrtf(ssum1 * (1.0f / CC) - mean1 * mean1 + EPSV);

    ushort* ap = a_out + (size_t)b * CC * SS + s;
    ushort* vp = v_out + (size_t)b * CC * SS + s;
    #pragma unroll 4
    for (int c = 0; c < CC; ++c) {
        float2 v = *(const float2*)(xsp + (size_t)c * SS);
        float2 t = *(const float2*)(xtp + (size_t)c * SS);
        float xn0 = (v.x - mean0) * rstd0 * w_all[0][c] + w_all[1][c];
        float xn1 = (v.y - mean1) * rstd1 * w_all[0][c] + w_all[1][c];
        float qk0 = xn0 * w_all[2][c] + w_all[3][c] + t.x * w_all[4][c] + w_all[5][c];
        float qk1 = xn1 * w_all[2][c] + w_all[3][c] + t.y * w_all[4][c] + w_all[5][c];
        float vv0 = xn0 * w_all[6][c] + w_all[7][c] + t.x * w_all[8][c] + w_all[9][c];
        float vv1 = xn1 * w_all[6][c] + w_all[7][c] + t.y * w_all[8][c] + w_all[9][c];
        float a0 = qk0 / (1.f + __expf(-qk0));
        float a1 = qk1 / (1.f + __expf(-qk1));
        *(unsigned*)(ap + (size_t)c * SS) = pack_bf16x2(a0, a1);
        *(unsigned*)(vp + (size_t)c * SS) = pack_bf16x2(vv0, vv1);
    }
}

// ---------------- K2: depthwise dilated conv + gate + ssq ------------------
// Block: (bc, 4 od planes, 24 oh rows), 576 threads; thread owns 8-w strip.
// LDS tile: 10 planes x 30 rows x 56 ushorts (row = 4 zero | 48 data | 4 zero)
#define ODT 4
#define OHT 24
#define NP 10
#define NR 30
#define RSD 28        // row stride in dwords
#define PSD (NR*RSD)  // 840 plane stride in dwords
#define TILE_DW (NP*PSD)  // 8400 dwords = 33.6 KB

__global__ __launch_bounds__(576, 2) void k2_conv(
    const ushort* __restrict__ a_in, const ushort* __restrict__ v_in,
    const float* __restrict__ attn_w, const float* __restrict__ attn_b,
    ushort* __restrict__ x_out, float* __restrict__ ssq)
{
    __shared__ unsigned tile[TILE_DW];
    __shared__ float wts[64];
    int tid = threadIdx.x;
    int blk = blockIdx.x;                 // bc*16 + odc*2 + ohc
    int bc = blk >> 4;
    int rem = blk & 15;
    int d0 = (rem >> 1) * ODT;
    int h0 = (rem & 1) * OHT;
    int c = bc % CC;

    // ---- stage tile (uint2 = 4 bf16), zero halo ----
    const ushort* abase = a_in + (size_t)bc * SS;
    for (int i2 = tid; i2 < TILE_DW / 2; i2 += 576) {
        int i = i2 * 2;
        int p = i / PSD;
        int r2 = i - p * PSD;
        int r = r2 / RSD;
        int q2 = r2 - r * RSD;            // even
        int id = d0 - 3 + p;
        int ih = h0 - 3 + r;
        int iw = q2 * 2 - 4;              // multiple of 4
        uint2 val = make_uint2(0u, 0u);
        if ((unsigned)id < (unsigned)DD && (unsigned)ih < (unsigned)HH &&
            (unsigned)iw < 45u)
            val = *(const uint2*)(abase + (size_t)id * HWs + ih * WW + iw);
        *(uint2*)&tile[i] = val;
    }
    if (tid < 64) wts[tid] = attn_w[c * 64 + tid];
    __syncthreads();
    float bias = attn_b[c];

    // thread -> (strip, oh, od):  576 = 6 strips * 24 rows * 4 planes
    int strip = tid % 6;
    int ohl = (tid / 6) % 24;
    int odl = tid / 144;
    int ow0 = strip * 8;

    float acc[8];
    #pragma unroll
    for (int j = 0; j < 8; ++j) acc[j] = 0.f;

    #pragma unroll
    for (int kd = 0; kd < 4; ++kd) {
        int p = odl + 2 * kd;
        #pragma unroll
        for (int kh = 0; kh < 4; ++kh) {
            int r = ohl + 2 * kh;
            int bd = p * PSD + r * RSD + strip * 4;
            unsigned u[8];
            *(uint4*)&u[0] = *(const uint4*)&tile[bd];
            *(uint4*)&u[4] = *(const uint4*)&tile[bd + 4];
            float wf[16];
            #pragma unroll
            for (int m = 0; m < 8; ++m) {
                wf[2*m]   = bf16_lo(u[m]);
                wf[2*m+1] = bf16_hi(u[m]);
            }
            float4 wv = *(const float4*)&wts[(kd * 4 + kh) * 4];
            #pragma unroll
            for (int j = 0; j < 8; ++j) {
                float a0 = fmaf(wf[j + 1], wv.x, acc[j]);
                float a1 = fmaf(wf[j + 3], wv.y, a0);
                float a2 = fmaf(wf[j + 5], wv.z, a1);
                acc[j]   = fmaf(wf[j + 7], wv.w, a2);
            }
        }
    }

    // ---- epilogue: x = (conv+bias)*v, ssq ----
    int od = d0 + odl, oh = h0 + ohl;
    size_t g = (size_t)bc * SS + (size_t)od * HWs + oh * WW + ow0;
    unsigned uv[4];
    *(uint4*)&uv[0] = *(const uint4*)(v_in + g);
    float ssql = 0.f;
    ushort pk[8];
    #pragma unroll
    for (int m = 0; m < 4; ++m) {
        float v0 = bf16_lo(uv[m]);
        float v1 = bf16_hi(uv[m]);
        float x0 = (acc[2*m]     + bias) * v0;
        float x1 = (acc[2*m + 1] + bias) * v1;
        ssql += x0 * x0 + x1 * x1;
        pk[2*m]     = pack_bf16(x0);
        pk[2*m + 1] = pack_bf16(x1);
    }
    *(uint4*)&x_out[g] = *(uint4*)&pk[0];

    // ---- per-wave reduce, one atomic per wave ----
    #pragma unroll
    for (int off = 32; off > 0; off >>= 1)
        ssql += __shfl_down(ssql, off);
    if ((tid & 63) == 0) atomicAdd(&ssq[bc], ssql);
}

// ---------------- K3: GRN scalars -> per-(b,c) A, B2 ----------------------
__global__ __launch_bounds__(384) void k3_scale(
    const float* __restrict__ ssq,
    const float* __restrict__ grn_gamma, const float* __restrict__ grn_beta,
    const float* __restrict__ proj_w, const float* __restrict__ proj_b,
    float* __restrict__ AB)
{
    __shared__ float gxs[BB*CC];
    __shared__ float msum[BB];
    int tid = threadIdx.x;     // 384
    float gx = sqrtf(ssq[tid]);
    gxs[tid] = gx;
    __syncthreads();
    if (tid < BB) {
        float s = 0.f;
        for (int c2 = 0; c2 < CC; ++c2) s += gxs[tid * CC + c2];
        msum[tid] = s * (1.0f / CC);
    }
    __syncthreads();
    int b = tid / CC, c2 = tid % CC;
    float nx = gx / (msum[b] + EPSV);
    float A  = proj_w[c2] * (1.f + grn_gamma[c2] * nx);
    float B2 = proj_w[c2] * grn_beta[c2] + proj_b[c2];
    AB[tid] = A;
    AB[BB*CC + tid] = B2;
}

// ---------------- K4: out = xs + A*x + B2 ---------------------------------
__global__ __launch_bounds__(256) void k4_final(
    const float* __restrict__ xs, const ushort* __restrict__ xv,
    const float* __restrict__ AB, float* __restrict__ out)
{
    int i = blockIdx.x * 256 + threadIdx.x;    // 8-elem index
    size_t g = (size_t)i * 8;
    int bc = (int)(g / SS);
    float A  = AB[bc];
    float B2 = AB[BB*CC + bc];
    uint4 xr = *(const uint4*)&xv[g];
    unsigned hx[4];
    *(uint4*)hx = xr;
    float4 s0 = *(const float4*)&xs[g];
    float4 s1 = *(const float4*)&xs[g + 4];
    float o[8];
    float sv[8] = {s0.x, s0.y, s0.z, s0.w, s1.x, s1.y, s1.z, s1.w};
    #pragma unroll
    for (int m = 0; m < 4; ++m) {
        o[2*m]   = fmaf(A, bf16_lo(hx[m]), sv[2*m])   + B2;
        o[2*m+1] = fmaf(A, bf16_hi(hx[m]), sv[2*m+1]) + B2;
    }
    *(float4*)&out[g]     = ((float4*)o)[0];
    *(float4*)&out[g + 4] = ((float4*)o)[1];
}

extern "C" void kernel_launch(void* const* d_in, const int* in_sizes, int n_in,
                              void* d_out, int out_size, void* d_ws, size_t ws_size,
                              hipStream_t stream) {
    const float* xs      = (const float*)d_in[0];
    const float* xt      = (const float*)d_in[1];
    const float* ln_w    = (const float*)d_in[2];
    const float* ln_b    = (const float*)d_in[3];
    const float* qk_sp_w = (const float*)d_in[4];
    const float* qk_sp_b = (const float*)d_in[5];
    const float* v_sp_w  = (const float*)d_in[6];
    const float* v_sp_b  = (const float*)d_in[7];
    const float* qk_tm_w = (const float*)d_in[8];
    const float* qk_tm_b = (const float*)d_in[9];
    const float* v_tm_w  = (const float*)d_in[10];
    const float* v_tm_b  = (const float*)d_in[11];
    const float* attn_w  = (const float*)d_in[12];
    const float* attn_b  = (const float*)d_in[13];
    const float* grn_g   = (const float*)d_in[14];
    const float* grn_b   = (const float*)d_in[15];
    const float* proj_w  = (const float*)d_in[16];
    const float* proj_b  = (const float*)d_in[17];
    float* out = (float*)d_out;

    ushort* a_buf = (ushort*)d_ws;                    // NTOT bf16
    ushort* v_buf = a_buf + (size_t)NTOT;             // NTOT bf16
    ushort* x_buf = v_buf + (size_t)NTOT;             // NTOT bf16
    float* ssq    = (float*)(x_buf + (size_t)NTOT);   // BB*CC
    float* AB     = ssq + BB*CC;                      // 2*BB*CC

    hipMemsetAsync(ssq, 0, BB*CC*sizeof(float), stream);

    k1_ln_av<<<BS/512, 256, 0, stream>>>(xs, xt, ln_w, ln_b,
        qk_sp_w, qk_sp_b, v_sp_w, v_sp_b,
        qk_tm_w, qk_tm_b, v_tm_w, v_tm_b, a_buf, v_buf);

    k2_conv<<<BB*CC*16, 576, 0, stream>>>(a_buf, v_buf,
        attn_w, attn_b, x_buf, ssq);

    k3_scale<<<1, 384, 0, stream>>>(ssq, grn_g, grn_b, proj_w, proj_b, AB);

    k4_final<<<NTOT/8/256, 256, 0, stream>>>(xs, x_buf, AB, out);
}

// Round 12
// 665.545 us; speedup vs baseline: 1.9227x; 1.0650x over previous
//
#include <hip/hip_runtime.h>
#include <math.h>

#define BB 2
#define CC 192
#define DD 32
#define HH 48
#define WW 48
#define HWs (HH*WW)            // 2304
#define SS (DD*HH*WW)          // 73728
#define BS (BB*SS)             // 147456
#define NTOT (BB*CC*SS)        // 28311552
#define EPSV 1e-6f

typedef unsigned short ushort;

__device__ __forceinline__ ushort pack_bf16(float x) {
    unsigned u = __float_as_uint(x);
    u += 0x7FFFu + ((u >> 16) & 1u);
    return (ushort)(u >> 16);
}
__device__ __forceinline__ unsigned pack_bf16x2(float lo, float hi) {
    return (unsigned)pack_bf16(lo) | ((unsigned)pack_bf16(hi) << 16);
}
__device__ __forceinline__ float bf16_lo(unsigned u) { return __uint_as_float(u << 16); }
__device__ __forceinline__ float bf16_hi(unsigned u) { return __uint_as_float(u & 0xFFFF0000u); }

// ---------------- K1: LayerNorm + a = silu(qk), v (both bf16) --------------
// Block: 256 thr = 4 waves. 128 positions (64 lanes x float2); each wave owns
// 48 channels; cross-wave stat reduce in LDS. 1152 blocks (4.5/CU).
#define CG 48
__global__ __launch_bounds__(256) void k1_ln_av(
    const float* __restrict__ xs, const float* __restrict__ xt,
    const float* __restrict__ ln_w, const float* __restrict__ ln_b,
    const float* __restrict__ qk_sp_w, const float* __restrict__ qk_sp_b,
    const float* __restrict__ v_sp_w, const float* __restrict__ v_sp_b,
    const float* __restrict__ qk_tm_w, const float* __restrict__ qk_tm_b,
    const float* __restrict__ v_tm_w, const float* __restrict__ v_tm_b,
    ushort* __restrict__ a_out, ushort* __restrict__ v_out)
{
    __shared__ float w_all[10][CC];
    __shared__ float2 sred[2][4][64];
    int tid = threadIdx.x;
    if (tid < CC) {
        w_all[0][tid] = ln_w[tid];    w_all[1][tid] = ln_b[tid];
        w_all[2][tid] = qk_sp_w[tid]; w_all[3][tid] = qk_sp_b[tid];
        w_all[4][tid] = qk_tm_w[tid]; w_all[5][tid] = qk_tm_b[tid];
        w_all[6][tid] = v_sp_w[tid];  w_all[7][tid] = v_sp_b[tid];
        w_all[8][tid] = v_tm_w[tid];  w_all[9][tid] = v_tm_b[tid];
    }
    __syncthreads();

    int tx = tid & 63, wy = tid >> 6;
    int p0 = blockIdx.x * 128;             // SS % 128 == 0 -> one b per block
    int b = p0 / SS;
    int s = (p0 % SS) + tx * 2;

    const float* xsp = xs + ((size_t)b * CC + wy * CG) * SS + s;
    const float* xtp = xt + ((size_t)b * CC + wy * CG) * SS + s;

    float2 sum = make_float2(0.f, 0.f), ssum = make_float2(0.f, 0.f);
    #pragma unroll 8
    for (int i = 0; i < CG; ++i) {
        float2 v = *(const float2*)(xsp + (size_t)i * SS);
        sum.x += v.x; ssum.x += v.x * v.x;
        sum.y += v.y; ssum.y += v.y * v.y;
    }
    sred[0][wy][tx] = sum;
    sred[1][wy][tx] = ssum;
    __syncthreads();
    float2 S = make_float2(0.f, 0.f), Q = make_float2(0.f, 0.f);
    #pragma unroll
    for (int w = 0; w < 4; ++w) {
        float2 a = sred[0][w][tx]; S.x += a.x; S.y += a.y;
        float2 q = sred[1][w][tx]; Q.x += q.x; Q.y += q.y;
    }
    float mean0 = S.x * (1.0f / CC), mean1 = S.y * (1.0f / CC);
    float rstd0 = rsqrtf(Q.x * (1.0f / CC) - mean0 * mean0 + EPSV);
    float rstd1 = rsqrtf(Q.y * (1.0f / CC) - mean1 * mean1 + EPSV);

    ushort* ap = a_out + ((size_t)b * CC + wy * CG) * SS + s;
    ushort* vp = v_out + ((size_t)b * CC + wy * CG) * SS + s;
    #pragma unroll 4
    for (int i = 0; i < CG; ++i) {
        int c = wy * CG + i;
        float2 v = *(const float2*)(xsp + (size_t)i * SS);
        float2 t = *(const float2*)(xtp + (size_t)i * SS);
        float xn0 = (v.x - mean0) * rstd0 * w_all[0][c] + w_all[1][c];
        float xn1 = (v.y - mean1) * rstd1 * w_all[0][c] + w_all[1][c];
        float qk0 = xn0 * w_all[2][c] + w_all[3][c] + t.x * w_all[4][c] + w_all[5][c];
        float qk1 = xn1 * w_all[2][c] + w_all[3][c] + t.y * w_all[4][c] + w_all[5][c];
        float vv0 = xn0 * w_all[6][c] + w_all[7][c] + t.x * w_all[8][c] + w_all[9][c];
        float vv1 = xn1 * w_all[6][c] + w_all[7][c] + t.y * w_all[8][c] + w_all[9][c];
        float a0 = qk0 / (1.f + __expf(-qk0));
        float a1 = qk1 / (1.f + __expf(-qk1));
        *(unsigned*)(ap + (size_t)i * SS) = pack_bf16x2(a0, a1);
        *(unsigned*)(vp + (size_t)i * SS) = pack_bf16x2(vv0, vv1);
    }
}

// ---------------- K2: depthwise dilated conv + gate + ssq ------------------
// Block: (bc, 4 od planes, 16 oh rows), 384 threads (6 waves); 8-w strip per
// thread. Tile 10 planes x 22 rows x 56 ushorts = 24.6 KB -> 4 blocks/CU.
#define ODT 4
#define OHT 16
#define NP 10
#define NR 22
#define RSD 28        // row stride in dwords
#define PSD (NR*RSD)  // 616 plane stride in dwords
#define TILE_DW (NP*PSD)  // 6160 dwords = 24.6 KB

__global__ __launch_bounds__(384, 2) void k2_conv(
    const ushort* __restrict__ a_in, const ushort* __restrict__ v_in,
    const float* __restrict__ attn_w, const float* __restrict__ attn_b,
    ushort* __restrict__ x_out, float* __restrict__ ssq)
{
    __shared__ unsigned tile[TILE_DW];
    __shared__ float wts[64];
    int tid = threadIdx.x;
    int blk = blockIdx.x;                 // bc*24 + dc*3 + hc
    int bc = blk / 24;
    int rem = blk % 24;
    int d0 = (rem / 3) * ODT;
    int h0 = (rem % 3) * OHT;
    int c = bc % CC;

    // ---- stage tile (uint2 = 4 bf16), zero halo ----
    const ushort* abase = a_in + (size_t)bc * SS;
    for (int i2 = tid; i2 < TILE_DW / 2; i2 += 384) {
        int i = i2 * 2;
        int p = i / PSD;
        int r2 = i - p * PSD;
        int r = r2 / RSD;
        int q2 = r2 - r * RSD;            // even
        int id = d0 - 3 + p;
        int ih = h0 - 3 + r;
        int iw = q2 * 2 - 4;              // multiple of 4
        uint2 val = make_uint2(0u, 0u);
        if ((unsigned)id < (unsigned)DD && (unsigned)ih < (unsigned)HH &&
            (unsigned)iw < 45u)
            val = *(const uint2*)(abase + (size_t)id * HWs + ih * WW + iw);
        *(uint2*)&tile[i] = val;
    }
    if (tid < 64) wts[tid] = attn_w[c * 64 + tid];
    __syncthreads();
    float bias = attn_b[c];

    // thread -> (strip, oh, od):  384 = 6 strips * 16 rows * 4 planes
    int strip = tid % 6;
    int ohl = (tid / 6) % 16;
    int odl = tid / 96;
    int ow0 = strip * 8;

    float acc[8];
    #pragma unroll
    for (int j = 0; j < 8; ++j) acc[j] = 0.f;

    #pragma unroll
    for (int kd = 0; kd < 4; ++kd) {
        int p = odl + 2 * kd;
        #pragma unroll
        for (int kh = 0; kh < 4; ++kh) {
            int r = ohl + 2 * kh;
            int bd = p * PSD + r * RSD + strip * 4;
            unsigned u[8];
            *(uint4*)&u[0] = *(const uint4*)&tile[bd];
            *(uint4*)&u[4] = *(const uint4*)&tile[bd + 4];
            float wf[16];
            #pragma unroll
            for (int m = 0; m < 8; ++m) {
                wf[2*m]   = bf16_lo(u[m]);
                wf[2*m+1] = bf16_hi(u[m]);
            }
            float4 wv = *(const float4*)&wts[(kd * 4 + kh) * 4];
            #pragma unroll
            for (int j = 0; j < 8; ++j) {
                float a0 = fmaf(wf[j + 1], wv.x, acc[j]);
                float a1 = fmaf(wf[j + 3], wv.y, a0);
                float a2 = fmaf(wf[j + 5], wv.z, a1);
                acc[j]   = fmaf(wf[j + 7], wv.w, a2);
            }
        }
    }

    // ---- epilogue: x = (conv+bias)*v, ssq ----
    int od = d0 + odl, oh = h0 + ohl;
    size_t g = (size_t)bc * SS + (size_t)od * HWs + oh * WW + ow0;
    unsigned uv[4];
    *(uint4*)&uv[0] = *(const uint4*)(v_in + g);
    float ssql = 0.f;
    ushort pk[8];
    #pragma unroll
    for (int m = 0; m < 4; ++m) {
        float v0 = bf16_lo(uv[m]);
        float v1 = bf16_hi(uv[m]);
        float x0 = (acc[2*m]     + bias) * v0;
        float x1 = (acc[2*m + 1] + bias) * v1;
        ssql += x0 * x0 + x1 * x1;
        pk[2*m]     = pack_bf16(x0);
        pk[2*m + 1] = pack_bf16(x1);
    }
    *(uint4*)&x_out[g] = *(uint4*)&pk[0];

    // ---- per-wave reduce, one atomic per wave ----
    #pragma unroll
    for (int off = 32; off > 0; off >>= 1)
        ssql += __shfl_down(ssql, off);
    if ((tid & 63) == 0) atomicAdd(&ssq[bc], ssql);
}

// ---------------- K3: GRN scalars -> per-(b,c) A, B2 ----------------------
__global__ __launch_bounds__(384) void k3_scale(
    const float* __restrict__ ssq,
    const float* __restrict__ grn_gamma, const float* __restrict__ grn_beta,
    const float* __restrict__ proj_w, const float* __restrict__ proj_b,
    float* __restrict__ AB)
{
    __shared__ float gxs[BB*CC];
    __shared__ float msum[BB];
    int tid = threadIdx.x;     // 384
    float gx = sqrtf(ssq[tid]);
    gxs[tid] = gx;
    __syncthreads();
    if (tid < BB) {
        float s = 0.f;
        for (int c2 = 0; c2 < CC; ++c2) s += gxs[tid * CC + c2];
        msum[tid] = s * (1.0f / CC);
    }
    __syncthreads();
    int b = tid / CC, c2 = tid % CC;
    float nx = gx / (msum[b] + EPSV);
    float A  = proj_w[c2] * (1.f + grn_gamma[c2] * nx);
    float B2 = proj_w[c2] * grn_beta[c2] + proj_b[c2];
    AB[tid] = A;
    AB[BB*CC + tid] = B2;
}

// ---------------- K4: out = xs + A*x + B2 ---------------------------------
__global__ __launch_bounds__(256) void k4_final(
    const float* __restrict__ xs, const ushort* __restrict__ xv,
    const float* __restrict__ AB, float* __restrict__ out)
{
    int i = blockIdx.x * 256 + threadIdx.x;    // 8-elem index
    size_t g = (size_t)i * 8;
    int bc = (int)(g / SS);
    float A  = AB[bc];
    float B2 = AB[BB*CC + bc];
    uint4 xr = *(const uint4*)&xv[g];
    unsigned hx[4];
    *(uint4*)hx = xr;
    float4 s0 = *(const float4*)&xs[g];
    float4 s1 = *(const float4*)&xs[g + 4];
    float o[8];
    float sv[8] = {s0.x, s0.y, s0.z, s0.w, s1.x, s1.y, s1.z, s1.w};
    #pragma unroll
    for (int m = 0; m < 4; ++m) {
        o[2*m]   = fmaf(A, bf16_lo(hx[m]), sv[2*m])   + B2;
        o[2*m+1] = fmaf(A, bf16_hi(hx[m]), sv[2*m+1]) + B2;
    }
    *(float4*)&out[g]     = ((float4*)o)[0];
    *(float4*)&out[g + 4] = ((float4*)o)[1];
}

extern "C" void kernel_launch(void* const* d_in, const int* in_sizes, int n_in,
                              void* d_out, int out_size, void* d_ws, size_t ws_size,
                              hipStream_t stream) {
    const float* xs      = (const float*)d_in[0];
    const float* xt      = (const float*)d_in[1];
    const float* ln_w    = (const float*)d_in[2];
    const float* ln_b    = (const float*)d_in[3];
    const float* qk_sp_w = (const float*)d_in[4];
    const float* qk_sp_b = (const float*)d_in[5];
    const float* v_sp_w  = (const float*)d_in[6];
    const float* v_sp_b  = (const float*)d_in[7];
    const float* qk_tm_w = (const float*)d_in[8];
    const float* qk_tm_b = (const float*)d_in[9];
    const float* v_tm_w  = (const float*)d_in[10];
    const float* v_tm_b  = (const float*)d_in[11];
    const float* attn_w  = (const float*)d_in[12];
    const float* attn_b  = (const float*)d_in[13];
    const float* grn_g   = (const float*)d_in[14];
    const float* grn_b   = (const float*)d_in[15];
    const float* proj_w  = (const float*)d_in[16];
    const float* proj_b  = (const float*)d_in[17];
    float* out = (float*)d_out;

    ushort* a_buf = (ushort*)d_ws;                    // NTOT bf16
    ushort* v_buf = a_buf + (size_t)NTOT;             // NTOT bf16
    ushort* x_buf = v_buf + (size_t)NTOT;             // NTOT bf16
    float* ssq    = (float*)(x_buf + (size_t)NTOT);   // BB*CC
    float* AB     = ssq + BB*CC;                      // 2*BB*CC

    hipMemsetAsync(ssq, 0, BB*CC*sizeof(float), stream);

    k1_ln_av<<<BS/128, 256, 0, stream>>>(xs, xt, ln_w, ln_b,
        qk_sp_w, qk_sp_b, v_sp_w, v_sp_b,
        qk_tm_w, qk_tm_b, v_tm_w, v_tm_b, a_buf, v_buf);

    k2_conv<<<BB*CC*24, 384, 0, stream>>>(a_buf, v_buf,
        attn_w, attn_b, x_buf, ssq);

    k3_scale<<<1, 384, 0, stream>>>(ssq, grn_g, grn_b, proj_w, proj_b, AB);

    k4_final<<<NTOT/8/256, 256, 0, stream>>>(xs, x_buf, AB, out);
}

// Round 14
// 660.566 us; speedup vs baseline: 1.9372x; 1.0075x over previous
//
#include <hip/hip_runtime.h>
#include <math.h>

#define BB 2
#define CC 192
#define DD 32
#define HH 48
#define WW 48
#define HWs (HH*WW)            // 2304
#define SS (DD*HH*WW)          // 73728
#define BS (BB*SS)             // 147456
#define NTOT (BB*CC*SS)        // 28311552
#define EPSV 1e-6f

typedef unsigned short ushort;
typedef float f2v __attribute__((ext_vector_type(2)));
typedef float f4v __attribute__((ext_vector_type(4)));

__device__ __forceinline__ ushort pack_bf16(float x) {
    unsigned u = __float_as_uint(x);
    u += 0x7FFFu + ((u >> 16) & 1u);
    return (ushort)(u >> 16);
}
__device__ __forceinline__ unsigned pack_bf16x2(float lo, float hi) {
    return (unsigned)pack_bf16(lo) | ((unsigned)pack_bf16(hi) << 16);
}
__device__ __forceinline__ float bf16_lo(unsigned u) { return __uint_as_float(u << 16); }
__device__ __forceinline__ float bf16_hi(unsigned u) { return __uint_as_float(u & 0xFFFF0000u); }

// non-temporal loads (keep L2/L3 from caching single-use streams)
__device__ __forceinline__ float2 nt_load2(const float* p) {
    f2v v = __builtin_nontemporal_load((const f2v*)p);
    return make_float2(v[0], v[1]);
}
__device__ __forceinline__ float4 nt_load4(const float* p) {
    f4v v = __builtin_nontemporal_load((const f4v*)p);
    return make_float4(v[0], v[1], v[2], v[3]);
}

// ---------------- K1: LayerNorm + a = silu(qk), v (both bf16) --------------
// Block: 256 thr = 4 waves. 128 positions (64 lanes x float2); each wave owns
// 48 channels; cross-wave stat reduce in LDS. 1152 blocks (4.5/CU).
// xt is single-use -> NT load, so L3 keeps xs + a/v for k2/k4.
#define CG 48
__global__ __launch_bounds__(256) void k1_ln_av(
    const float* __restrict__ xs, const float* __restrict__ xt,
    const float* __restrict__ ln_w, const float* __restrict__ ln_b,
    const float* __restrict__ qk_sp_w, const float* __restrict__ qk_sp_b,
    const float* __restrict__ v_sp_w, const float* __restrict__ v_sp_b,
    const float* __restrict__ qk_tm_w, const float* __restrict__ qk_tm_b,
    const float* __restrict__ v_tm_w, const float* __restrict__ v_tm_b,
    ushort* __restrict__ a_out, ushort* __restrict__ v_out)
{
    __shared__ float w_all[10][CC];
    __shared__ float2 sred[2][4][64];
    int tid = threadIdx.x;
    if (tid < CC) {
        w_all[0][tid] = ln_w[tid];    w_all[1][tid] = ln_b[tid];
        w_all[2][tid] = qk_sp_w[tid]; w_all[3][tid] = qk_sp_b[tid];
        w_all[4][tid] = qk_tm_w[tid]; w_all[5][tid] = qk_tm_b[tid];
        w_all[6][tid] = v_sp_w[tid];  w_all[7][tid] = v_sp_b[tid];
        w_all[8][tid] = v_tm_w[tid];  w_all[9][tid] = v_tm_b[tid];
    }
    __syncthreads();

    int tx = tid & 63, wy = tid >> 6;
    int p0 = blockIdx.x * 128;             // SS % 128 == 0 -> one b per block
    int b = p0 / SS;
    int s = (p0 % SS) + tx * 2;

    const float* xsp = xs + ((size_t)b * CC + wy * CG) * SS + s;
    const float* xtp = xt + ((size_t)b * CC + wy * CG) * SS + s;

    float2 sum = make_float2(0.f, 0.f), ssum = make_float2(0.f, 0.f);
    #pragma unroll 8
    for (int i = 0; i < CG; ++i) {
        float2 v = *(const float2*)(xsp + (size_t)i * SS);
        sum.x += v.x; ssum.x += v.x * v.x;
        sum.y += v.y; ssum.y += v.y * v.y;
    }
    sred[0][wy][tx] = sum;
    sred[1][wy][tx] = ssum;
    __syncthreads();
    float2 S = make_float2(0.f, 0.f), Q = make_float2(0.f, 0.f);
    #pragma unroll
    for (int w = 0; w < 4; ++w) {
        float2 a = sred[0][w][tx]; S.x += a.x; S.y += a.y;
        float2 q = sred[1][w][tx]; Q.x += q.x; Q.y += q.y;
    }
    float mean0 = S.x * (1.0f / CC), mean1 = S.y * (1.0f / CC);
    float rstd0 = rsqrtf(Q.x * (1.0f / CC) - mean0 * mean0 + EPSV);
    float rstd1 = rsqrtf(Q.y * (1.0f / CC) - mean1 * mean1 + EPSV);

    ushort* ap = a_out + ((size_t)b * CC + wy * CG) * SS + s;
    ushort* vp = v_out + ((size_t)b * CC + wy * CG) * SS + s;
    #pragma unroll 4
    for (int i = 0; i < CG; ++i) {
        int c = wy * CG + i;
        float2 v = *(const float2*)(xsp + (size_t)i * SS);
        float2 t = nt_load2(xtp + (size_t)i * SS);
        float xn0 = (v.x - mean0) * rstd0 * w_all[0][c] + w_all[1][c];
        float xn1 = (v.y - mean1) * rstd1 * w_all[0][c] + w_all[1][c];
        float qk0 = xn0 * w_all[2][c] + w_all[3][c] + t.x * w_all[4][c] + w_all[5][c];
        float qk1 = xn1 * w_all[2][c] + w_all[3][c] + t.y * w_all[4][c] + w_all[5][c];
        float vv0 = xn0 * w_all[6][c] + w_all[7][c] + t.x * w_all[8][c] + w_all[9][c];
        float vv1 = xn1 * w_all[6][c] + w_all[7][c] + t.y * w_all[8][c] + w_all[9][c];
        float a0 = qk0 / (1.f + __expf(-qk0));
        float a1 = qk1 / (1.f + __expf(-qk1));
        *(unsigned*)(ap + (size_t)i * SS) = pack_bf16x2(a0, a1);
        *(unsigned*)(vp + (size_t)i * SS) = pack_bf16x2(vv0, vv1);
    }
}

// ---------------- K2: depthwise dilated conv + gate + ssq ------------------
// Block: (bc, 4 od planes, 16 oh rows), 384 threads (6 waves); 8-w strip per
// thread. Tile 10 planes x 22 rows x 56 ushorts = 24.6 KB.
// v_in load issued BEFORE the barrier so it hides under staging+conv.
#define ODT 4
#define OHT 16
#define NP 10
#define NR 22
#define RSD 28        // row stride in dwords
#define PSD (NR*RSD)  // 616 plane stride in dwords
#define TILE_DW (NP*PSD)  // 6160 dwords = 24.6 KB

__global__ __launch_bounds__(384, 2) void k2_conv(
    const ushort* __restrict__ a_in, const ushort* __restrict__ v_in,
    const float* __restrict__ attn_w, const float* __restrict__ attn_b,
    ushort* __restrict__ x_out, float* __restrict__ ssq)
{
    __shared__ unsigned tile[TILE_DW];
    __shared__ float wts[64];
    int tid = threadIdx.x;
    int blk = blockIdx.x;                 // bc*24 + dc*3 + hc
    int bc = blk / 24;
    int rem = blk % 24;
    int d0 = (rem / 3) * ODT;
    int h0 = (rem % 3) * OHT;
    int c = bc % CC;

    // thread -> (strip, oh, od):  384 = 6 strips * 16 rows * 4 planes
    int strip = tid % 6;
    int ohl = (tid / 6) % 16;
    int odl = tid / 96;
    int ow0 = strip * 8;
    int od = d0 + odl, oh = h0 + ohl;
    size_t g = (size_t)bc * SS + (size_t)od * HWs + oh * WW + ow0;

    // ---- stage tile (uint2 = 4 bf16), zero halo ----
    const ushort* abase = a_in + (size_t)bc * SS;
    for (int i2 = tid; i2 < TILE_DW / 2; i2 += 384) {
        int i = i2 * 2;
        int p = i / PSD;
        int r2 = i - p * PSD;
        int r = r2 / RSD;
        int q2 = r2 - r * RSD;            // even
        int id = d0 - 3 + p;
        int ih = h0 - 3 + r;
        int iw = q2 * 2 - 4;              // multiple of 4
        uint2 val = make_uint2(0u, 0u);
        if ((unsigned)id < (unsigned)DD && (unsigned)ih < (unsigned)HH &&
            (unsigned)iw < 45u)
            val = *(const uint2*)(abase + (size_t)id * HWs + ih * WW + iw);
        *(uint2*)&tile[i] = val;
    }
    if (tid < 64) wts[tid] = attn_w[c * 64 + tid];

    // prefetch v (latency hides under barrier + conv compute)
    unsigned uv[4];
    *(uint4*)&uv[0] = *(const uint4*)(v_in + g);
    float bias = attn_b[c];

    __syncthreads();

    float acc[8];
    #pragma unroll
    for (int j = 0; j < 8; ++j) acc[j] = 0.f;

    #pragma unroll
    for (int kd = 0; kd < 4; ++kd) {
        int p = odl + 2 * kd;
        #pragma unroll
        for (int kh = 0; kh < 4; ++kh) {
            int r = ohl + 2 * kh;
            int bd = p * PSD + r * RSD + strip * 4;
            unsigned u[8];
            *(uint4*)&u[0] = *(const uint4*)&tile[bd];
            *(uint4*)&u[4] = *(const uint4*)&tile[bd + 4];
            float wf[16];
            #pragma unroll
            for (int m = 0; m < 8; ++m) {
                wf[2*m]   = bf16_lo(u[m]);
                wf[2*m+1] = bf16_hi(u[m]);
            }
            float4 wv = *(const float4*)&wts[(kd * 4 + kh) * 4];
            #pragma unroll
            for (int j = 0; j < 8; ++j) {
                float a0 = fmaf(wf[j + 1], wv.x, acc[j]);
                float a1 = fmaf(wf[j + 3], wv.y, a0);
                float a2 = fmaf(wf[j + 5], wv.z, a1);
                acc[j]   = fmaf(wf[j + 7], wv.w, a2);
            }
        }
    }

    // ---- epilogue: x = (conv+bias)*v, ssq ----
    float ssql = 0.f;
    ushort pk[8];
    #pragma unroll
    for (int m = 0; m < 4; ++m) {
        float v0 = bf16_lo(uv[m]);
        float v1 = bf16_hi(uv[m]);
        float x0 = (acc[2*m]     + bias) * v0;
        float x1 = (acc[2*m + 1] + bias) * v1;
        ssql += x0 * x0 + x1 * x1;
        pk[2*m]     = pack_bf16(x0);
        pk[2*m + 1] = pack_bf16(x1);
    }
    *(uint4*)&x_out[g] = *(uint4*)&pk[0];

    // ---- per-wave reduce, one atomic per wave ----
    #pragma unroll
    for (int off = 32; off > 0; off >>= 1)
        ssql += __shfl_down(ssql, off);
    if ((tid & 63) == 0) atomicAdd(&ssq[bc], ssql);
}

// ---------------- K3: GRN scalars -> per-(b,c) A, B2 ----------------------
__global__ __launch_bounds__(384) void k3_scale(
    const float* __restrict__ ssq,
    const float* __restrict__ grn_gamma, const float* __restrict__ grn_beta,
    const float* __restrict__ proj_w, const float* __restrict__ proj_b,
    float* __restrict__ AB)
{
    __shared__ float gxs[BB*CC];
    __shared__ float msum[BB];
    int tid = threadIdx.x;     // 384
    float gx = sqrtf(ssq[tid]);
    gxs[tid] = gx;
    __syncthreads();
    if (tid < BB) {
        float s = 0.f;
        for (int c2 = 0; c2 < CC; ++c2) s += gxs[tid * CC + c2];
        msum[tid] = s * (1.0f / CC);
    }
    __syncthreads();
    int b = tid / CC, c2 = tid % CC;
    float nx = gx / (msum[b] + EPSV);
    float A  = proj_w[c2] * (1.f + grn_gamma[c2] * nx);
    float B2 = proj_w[c2] * grn_beta[c2] + proj_b[c2];
    AB[tid] = A;
    AB[BB*CC + tid] = B2;
}

// ---------------- K4: out = xs + A*x + B2 ---------------------------------
__global__ __launch_bounds__(256) void k4_final(
    const float* __restrict__ xs, const ushort* __restrict__ xv,
    const float* __restrict__ AB, float* __restrict__ out)
{
    int i = blockIdx.x * 256 + threadIdx.x;    // 8-elem index
    size_t g = (size_t)i * 8;
    int bc = (int)(g / SS);
    float A  = AB[bc];
    float B2 = AB[BB*CC + bc];
    uint4 xr = *(const uint4*)&xv[g];
    unsigned hx[4];
    *(uint4*)hx = xr;
    float4 s0 = nt_load4(&xs[g]);         // last consumer of xs -> NT
    float4 s1 = nt_load4(&xs[g + 4]);
    float o[8];
    float sv[8] = {s0.x, s0.y, s0.z, s0.w, s1.x, s1.y, s1.z, s1.w};
    #pragma unroll
    for (int m = 0; m < 4; ++m) {
        o[2*m]   = fmaf(A, bf16_lo(hx[m]), sv[2*m])   + B2;
        o[2*m+1] = fmaf(A, bf16_hi(hx[m]), sv[2*m+1]) + B2;
    }
    *(float4*)&out[g]     = ((float4*)o)[0];
    *(float4*)&out[g + 4] = ((float4*)o)[1];
}

extern "C" void kernel_launch(void* const* d_in, const int* in_sizes, int n_in,
                              void* d_out, int out_size, void* d_ws, size_t ws_size,
                              hipStream_t stream) {
    const float* xs      = (const float*)d_in[0];
    const float* xt      = (const float*)d_in[1];
    const float* ln_w    = (const float*)d_in[2];
    const float* ln_b    = (const float*)d_in[3];
    const float* qk_sp_w = (const float*)d_in[4];
    const float* qk_sp_b = (const float*)d_in[5];
    const float* v_sp_w  = (const float*)d_in[6];
    const float* v_sp_b  = (const float*)d_in[7];
    const float* qk_tm_w = (const float*)d_in[8];
    const float* qk_tm_b = (const float*)d_in[9];
    const float* v_tm_w  = (const float*)d_in[10];
    const float* v_tm_b  = (const float*)d_in[11];
    const float* attn_w  = (const float*)d_in[12];
    const float* attn_b  = (const float*)d_in[13];
    const float* grn_g   = (const float*)d_in[14];
    const float* grn_b   = (const float*)d_in[15];
    const float* proj_w  = (const float*)d_in[16];
    const float* proj_b  = (const float*)d_in[17];
    float* out = (float*)d_out;

    ushort* a_buf = (ushort*)d_ws;                    // NTOT bf16
    ushort* v_buf = a_buf + (size_t)NTOT;             // NTOT bf16
    ushort* x_buf = v_buf + (size_t)NTOT;             // NTOT bf16
    float* ssq    = (float*)(x_buf + (size_t)NTOT);   // BB*CC
    float* AB     = ssq + BB*CC;                      // 2*BB*CC

    hipMemsetAsync(ssq, 0, BB*CC*sizeof(float), stream);

    k1_ln_av<<<BS/128, 256, 0, stream>>>(xs, xt, ln_w, ln_b,
        qk_sp_w, qk_sp_b, v_sp_w, v_sp_b,
        qk_tm_w, qk_tm_b, v_tm_w, v_tm_b, a_buf, v_buf);

    k2_conv<<<BB*CC*24, 384, 0, stream>>>(a_buf, v_buf,
        attn_w, attn_b, x_buf, ssq);

    k3_scale<<<1, 384, 0, stream>>>(ssq, grn_g, grn_b, proj_w, proj_b, AB);

    k4_final<<<NTOT/8/256, 256, 0, stream>>>(xs, x_buf, AB, out);
}